// Round 15
// baseline (383.447 us; speedup 1.0000x reference)
//
#include <hip/hip_runtime.h>
#include <math.h>

#define NB 8
#define ND 128
#define NT 2048
#define NF 1025
#define NYY 256
#define NXX 256

#define SPEC_BYTES 8396800          /* 8*128*1025*8 */
#define BANDH_PART_BYTES 1048576    /* 8*128*256*4 (bf16x2 band part) */
#define BAND_PART_BYTES 2097152     /* fp32 bandS */

#define FPART 24
#define FLEN_BASE 43                /* ceil(1025/24) */
#define FPAD 44
#define GRID_BLKS 768               /* 256 CU x 3 blocks: co-resident by construction */

/* ws layout */
#define BAR_OFF     0               /* 64 B barrier counters */
#define ROWSTAT_OFF 1024            /* 8 KB */
#define SPECT_OFF   16384
#define SF_OFF      (SPECT_OFF + SPEC_BYTES)                 /* 8,413,184 */
#define BAND_OFF    (SF_OFF + SPEC_BYTES)                    /* 16,809,984 */
#define BANDS_OFF   (BAND_OFF + (size_t)FPART * BANDH_PART_BYTES)
#define NEED_MEGA   (BANDS_OFF + BAND_PART_BYTES)

__device__ __forceinline__ unsigned int bf16rne(float x) {
  unsigned int u = __float_as_uint(x);
  return (u + 0x7fffu + ((u >> 16) & 1u)) >> 16;
}

__device__ __forceinline__ void gridbar(unsigned* bar, int slot) {
  __syncthreads();
  if (threadIdx.x == 0) {
    __threadfence();                                   // release my writes
    atomicAdd(&bar[slot], 1u);
    while (__hip_atomic_load(&bar[slot], __ATOMIC_RELAXED, __HIP_MEMORY_SCOPE_AGENT)
           < (unsigned)GRID_BLKS) {
      __builtin_amdgcn_s_sleep(2);
    }
    __threadfence();                                   // acquire others' writes
  }
  __syncthreads();
}

// =================== persistent mega-kernel: 5 phases, 4 grid barriers ==========
__global__ __launch_bounds__(256, 3) void fk_mega(
    const float* __restrict__ sino, float2* __restrict__ specT,
    float2* __restrict__ rowstat, float2* __restrict__ sf,
    unsigned int* __restrict__ bandh, float2* __restrict__ bandS,
    float* __restrict__ out, unsigned* __restrict__ bar, float inv_norm) {
  __shared__ __align__(16) char smraw[16448];
  const int tid = threadIdx.x;

  // ---------- phase 1: tfft (1024 rows) + rowstat ----------
  {
    float2* bufA = (float2*)smraw;
    float2* bufB = bufA + 1024;
    float2* wsum = bufB + 1024;
    for (int vb = blockIdx.x; vb < NB * ND; vb += GRID_BLKS) {
      __syncthreads();
      const int row = vb;
      const int d = row & (ND - 1);
      const float ap = (float)(0.5 - 0.5 * cos(6.283185307179586 * (double)d / 127.0));
      const float2* in = (const float2*)(sino + (size_t)row * NT);
      float s = 0.f, q = 0.f;
      for (int i = tid; i < 1024; i += 256) {
        float2 v = in[i];
        s += v.x + v.y;
        q += v.x * v.x + v.y * v.y;
        bufA[i] = make_float2(v.x * ap, v.y * ap);
      }
      #pragma unroll
      for (int o = 32; o > 0; o >>= 1) {
        s += __shfl_down(s, o);
        q += __shfl_down(q, o);
      }
      if ((tid & 63) == 0) wsum[tid >> 6] = make_float2(s, q);
      __syncthreads();
      if (tid == 0)
        rowstat[row] = make_float2(wsum[0].x + wsum[1].x + wsum[2].x + wsum[3].x,
                                   wsum[0].y + wsum[1].y + wsum[2].y + wsum[3].y);
      float2* src = bufA;
      float2* dst = bufB;
      for (int p = 1; p <= 512; p <<= 1) {
        #pragma unroll
        for (int it = 0; it < 2; ++it) {
          int i = tid + it * 256;
          int k = i & (p - 1);
          float2 u = src[i];
          float2 v = src[i + 512];
          float ang = -3.14159265358979323846f * ((float)k / (float)p);
          float sn, cs; __sincosf(ang, &sn, &cs);
          float2 vw = make_float2(v.x * cs - v.y * sn, v.x * sn + v.y * cs);
          int j = ((i - k) << 1) + k;
          dst[j]     = make_float2(u.x + vw.x, u.y + vw.y);
          dst[j + p] = make_float2(u.x - vw.x, u.y - vw.y);
        }
        __syncthreads();
        float2* t = src; src = dst; dst = t;
      }
      float2* outp = specT + (size_t)row * NF;
      for (int k = tid; k < 1024; k += 256) {
        float2 zk = src[k];
        float2 zc = src[(1024 - k) & 1023]; zc.y = -zc.y;
        float2 xe = make_float2(0.5f * (zk.x + zc.x), 0.5f * (zk.y + zc.y));
        float ax = zk.x - zc.x, ay = zk.y - zc.y;
        float2 xo = make_float2(0.5f * ay, -0.5f * ax);
        float ang = -3.14159265358979323846f * ((float)k / 1024.0f);
        float sn, cs; __sincosf(ang, &sn, &cs);
        outp[k] = make_float2(xe.x + cs * xo.x - sn * xo.y,
                              xe.y + cs * xo.y + sn * xo.x);
      }
      if (tid == 0) {
        float2 z0 = src[0];
        outp[1024] = make_float2(z0.x - z0.y, 0.0f);
      }
    }
  }
  gridbar(bar, 0);

  // ---------- phase 2: detector FFT + mask*fw (257*8 virtual blocks) ----------
  {
    float2 (*A)[128]  = (float2 (*)[128])smraw;
    float2 (*Bf)[128] = (float2 (*)[128])(smraw + 4096);
    const int sub = tid >> 6;
    const int i = tid & 63;
    for (int vb = blockIdx.x; vb < 257 * 8; vb += GRID_BLKS) {
      __syncthreads();
      const int b = vb & 7;
      const int f0 = (vb >> 3) * 4;
      const int f = f0 + sub;
      const bool valid = (f < NF);
      if (valid) {
        const float2* col = specT + ((size_t)b * ND) * NF + f;
        A[sub][i]      = col[(size_t)i * NF];
        A[sub][i + 64] = col[(size_t)(i + 64) * NF];
      }
      __syncthreads();
      float2 (*src)[128] = A;
      float2 (*dst)[128] = Bf;
      for (int p = 1; p <= 64; p <<= 1) {
        if (valid) {
          int k = i & (p - 1);
          float2 u = src[sub][i];
          float2 v = src[sub][i + 64];
          float ang = -3.14159265358979323846f * ((float)k / (float)p);
          float sn, cs; __sincosf(ang, &sn, &cs);
          float2 vw = make_float2(v.x * cs - v.y * sn, v.x * sn + v.y * cs);
          int j = ((i - k) << 1) + k;
          dst[sub][j]     = make_float2(u.x + vw.x, u.y + vw.y);
          dst[sub][j + p] = make_float2(u.x - vw.x, u.y - vw.y);
        }
        __syncthreads();
        float2 (*t)[128] = src; src = dst; dst = t;
      }
      if (valid) {
        const float fwv = (f == 0 || f == NF - 1) ? 1.0f : 2.0f;
        double freqd = (double)f / 5.12e-5;
        float omega = (float)(freqd * 6.283185307179586);
        float woc = omega / 1540.0f;
        float woc2 = __fmul_rn(woc, woc);
        #pragma unroll
        for (int h = 0; h < 2; ++h) {
          int kd = i + h * 64;
          int kt = kd < 64 ? kd : kd - 128;
          float kxv = (float)(6.283185307179586 * ((double)kt / 0.0384));
          float kzsq = __fsub_rn(woc2, __fmul_rn(kxv, kxv));
          float m = (kzsq > 0.0f) ? fwv : 0.0f;
          float2 v = src[sub][kd];
          sf[((size_t)(b * ND + kd)) * NF + f] = make_float2(v.x * m, v.y * m);
        }
      }
    }
  }
  gridbar(bar, 1);

  // ---------- phase 3: band (768 virtual blocks == grid, one pass) ----------
  {
    float2* sfs = (float2*)smraw;                     // 32*FPAD float2 = 11264 B
    float4* kcs = (float4*)(smraw + 11264);           // 4*FPAD float4 = 2816 B
    const int vb = blockIdx.x;
    const int dblk = vb & 31;
    const int part = vb >> 5;
    const int f0 = part * FLEN_BASE;
    const int flen = min(FLEN_BASE, NF - f0);
    const int w = tid >> 6, l = tid & 63;
    const int d = dblk * 4 + w;

    {
      const int row = tid >> 3;
      const int wr = row >> 3, br = row & 7;
      const int dr = dblk * 4 + wr;
      const float2* srcp = sf + ((size_t)(br * ND + dr)) * NF + f0;
      for (int ff = tid & 7; ff < FPAD; ff += 8)
        sfs[row * FPAD + ff] = (ff < flen) ? srcp[ff] : make_float2(0.f, 0.f);
    }
    for (int e = tid; e < 4 * FPAD; e += 256) {
      const int wk = e / FPAD, ff = e - wk * FPAD;
      float kzv = 0.f;
      if (ff < flen) {
        int dk = dblk * 4 + wk;
        int kt = dk < 64 ? dk : dk - 128;
        float kxv = (float)(6.283185307179586 * ((double)kt / 0.0384));
        float kx2 = __fmul_rn(kxv, kxv);
        int f = f0 + ff;
        double freqd = (double)f / 5.12e-5;
        float omega = (float)(freqd * 6.283185307179586);
        float woc = omega / 1540.0f;
        float kzsq = __fsub_rn(__fmul_rn(woc, woc), kx2);
        kzv = (kzsq > 0.0f) ? sqrtf(kzsq) : 0.0f;
      }
      float sd, cd;
      __sincosf(kzv * 1.5e-4f, &sd, &cd);
      kcs[e] = make_float4(kzv, cd, sd, 0.f);
    }
    __syncthreads();

    const float y0 = (float)(1.0e-3 + (double)(4 * l) * 1.5e-4);
    float2 acc[8][4];
    #pragma unroll
    for (int b = 0; b < 8; ++b)
      #pragma unroll
      for (int i = 0; i < 4; ++i) acc[b][i] = make_float2(0.f, 0.f);

    const float4* kcw = kcs + w * FPAD;
    const float2* rows = sfs + (w * 8) * FPAD;

    #pragma unroll 2
    for (int ff = 0; ff < FPAD; ++ff) {
      const float4 k4 = kcw[ff];
      float s0, c0;
      __sincosf(k4.x * y0, &s0, &c0);
      float2 ph[4];
      ph[0] = make_float2(c0, s0);
      #pragma unroll
      for (int i = 0; i < 3; ++i)
        ph[i + 1] = make_float2(ph[i].x * k4.y - ph[i].y * k4.z,
                                ph[i].x * k4.z + ph[i].y * k4.y);
      #pragma unroll
      for (int b = 0; b < 8; ++b) {
        float2 p = rows[b * FPAD + ff];
        #pragma unroll
        for (int i = 0; i < 4; ++i) {
          acc[b][i].x = fmaf(p.x, ph[i].x, fmaf(-p.y, ph[i].y, acc[b][i].x));
          acc[b][i].y = fmaf(p.x, ph[i].y, fmaf( p.y, ph[i].x, acc[b][i].y));
        }
      }
    }

    unsigned int* outp = bandh + (size_t)part * (NB * ND * NYY);
    #pragma unroll
    for (int b = 0; b < 8; ++b) {
      uint4 pk;
      pk.x = bf16rne(acc[b][0].x) | (bf16rne(acc[b][0].y) << 16);
      pk.y = bf16rne(acc[b][1].x) | (bf16rne(acc[b][1].y) << 16);
      pk.z = bf16rne(acc[b][2].x) | (bf16rne(acc[b][2].y) << 16);
      pk.w = bf16rne(acc[b][3].x) | (bf16rne(acc[b][3].y) << 16);
      ((uint4*)(outp + ((size_t)(b * ND + d)) * NYY))[l] = pk;
    }
  }
  gridbar(bar, 2);

  // ---------- phase 4: sum over parts (2048 virtual blocks) ----------
  {
    for (int vb = blockIdx.x; vb < NB * ND * NYY / 256; vb += GRID_BLKS) {
      const int n = vb * 256 + tid;
      float sx = 0.f, sy = 0.f;
      for (int p = 0; p < FPART; ++p) {
        unsigned int u = bandh[(size_t)p * (NB * ND * NYY) + n];
        sx += __uint_as_float(u << 16);
        sy += __uint_as_float(u & 0xffff0000u);
      }
      bandS[n] = make_float2(sx, sy);
    }
  }
  gridbar(bar, 3);

  // ---------- phase 5: lateral 256-pt iFFT + |.| + scale (1024 virtual blocks) ----
  {
    float2 (*A2)[256]  = (float2 (*)[256])smraw;
    float2 (*Bb2)[256] = (float2 (*)[256])(smraw + 4096);
    float2* spart = (float2*)(smraw + 8192);
    const int half = tid >> 7;
    const int t = tid & 127;
    for (int vb = blockIdx.x; vb < (NYY / 2) * NB; vb += GRID_BLKS) {
      __syncthreads();
      const int y0 = (vb & 127) * 2;
      const int b = vb >> 7;
      {
        float2 v = bandS[((size_t)(b * ND + t)) * NYY + (y0 + half)];
        A2[half][t]       = (t < 64)  ? v : make_float2(0.f, 0.f);
        A2[half][t + 128] = (t >= 64) ? v : make_float2(0.f, 0.f);
      }
      {
        float2 myrs = make_float2(0.f, 0.f);
        if (tid < 128) myrs = rowstat[b * ND + tid];
        float s = myrs.x, q = myrs.y;
        #pragma unroll
        for (int o = 32; o > 0; o >>= 1) {
          s += __shfl_down(s, o);
          q += __shfl_down(q, o);
        }
        if (tid < 128 && (tid & 63) == 0) spart[tid >> 6] = make_float2(s, q);
      }
      __syncthreads();
      const float nInv = 1.0f / 262144.0f;
      float ssum = spart[0].x + spart[1].x;
      float qsum = spart[0].y + spart[1].y;
      float mean = ssum * nInv;
      float var = qsum * nInv - mean * mean;
      float scl = 1.0f / sqrtf(var + 1.1920928955078125e-7f);

      float2 (*src)[256] = A2;
      float2 (*dst)[256] = Bb2;
      for (int p = 1; p <= 128; p <<= 1) {
        int i = t;
        int k = i & (p - 1);
        float2 u = src[half][i];
        float2 v = src[half][i + 128];
        float ang = 3.14159265358979323846f * ((float)k / (float)p);
        float sn, cs; __sincosf(ang, &sn, &cs);
        float2 vw = make_float2(v.x * cs - v.y * sn, v.x * sn + v.y * cs);
        int j = ((i - k) << 1) + k;
        dst[half][j]     = make_float2(u.x + vw.x, u.y + vw.y);
        dst[half][j + p] = make_float2(u.x - vw.x, u.y - vw.y);
        __syncthreads();
        float2 (*tt)[256] = src; src = dst; dst = tt;
      }
      float2 r0 = src[0][tid];
      float2 r1 = src[1][tid];
      out[((size_t)b * NYY + y0)     * NXX + tid] =
          sqrtf(r0.x * r0.x + r0.y * r0.y) * scl * inv_norm;
      out[((size_t)b * NYY + y0 + 1) * NXX + tid] =
          sqrtf(r1.x * r1.x + r1.y * r1.y) * scl * inv_norm;
    }
  }
}

// =================== fallback 5-kernel path (small workspace) ==================
__global__ __launch_bounds__(256) void fk_tfft(const float* __restrict__ sino,
                                               float2* __restrict__ specT,
                                               float2* __restrict__ rowstat) {
  const int row = blockIdx.x;
  const int d = row & (ND - 1);
  const int tid = threadIdx.x;
  __shared__ float2 bufA[1024];
  __shared__ float2 bufB[1024];
  __shared__ float2 wsum[4];
  const float ap = (float)(0.5 - 0.5 * cos(6.283185307179586 * (double)d / 127.0));
  const float2* in = (const float2*)(sino + (size_t)row * NT);
  float s = 0.f, q = 0.f;
  for (int i = tid; i < 1024; i += 256) {
    float2 v = in[i];
    s += v.x + v.y;
    q += v.x * v.x + v.y * v.y;
    bufA[i] = make_float2(v.x * ap, v.y * ap);
  }
  #pragma unroll
  for (int o = 32; o > 0; o >>= 1) { s += __shfl_down(s, o); q += __shfl_down(q, o); }
  if ((tid & 63) == 0) wsum[tid >> 6] = make_float2(s, q);
  __syncthreads();
  if (tid == 0)
    rowstat[row] = make_float2(wsum[0].x + wsum[1].x + wsum[2].x + wsum[3].x,
                               wsum[0].y + wsum[1].y + wsum[2].y + wsum[3].y);
  float2* src = bufA;
  float2* dst = bufB;
  for (int p = 1; p <= 512; p <<= 1) {
    #pragma unroll
    for (int it = 0; it < 2; ++it) {
      int i = tid + it * 256;
      int k = i & (p - 1);
      float2 u = src[i];
      float2 v = src[i + 512];
      float ang = -3.14159265358979323846f * ((float)k / (float)p);
      float sn, cs; __sincosf(ang, &sn, &cs);
      float2 vw = make_float2(v.x * cs - v.y * sn, v.x * sn + v.y * cs);
      int j = ((i - k) << 1) + k;
      dst[j]     = make_float2(u.x + vw.x, u.y + vw.y);
      dst[j + p] = make_float2(u.x - vw.x, u.y - vw.y);
    }
    __syncthreads();
    float2* t = src; src = dst; dst = t;
  }
  float2* outp = specT + (size_t)row * NF;
  for (int k = tid; k < 1024; k += 256) {
    float2 zk = src[k];
    float2 zc = src[(1024 - k) & 1023]; zc.y = -zc.y;
    float2 xe = make_float2(0.5f * (zk.x + zc.x), 0.5f * (zk.y + zc.y));
    float ax = zk.x - zc.x, ay = zk.y - zc.y;
    float2 xo = make_float2(0.5f * ay, -0.5f * ax);
    float ang = -3.14159265358979323846f * ((float)k / 1024.0f);
    float sn, cs; __sincosf(ang, &sn, &cs);
    outp[k] = make_float2(xe.x + cs * xo.x - sn * xo.y,
                          xe.y + cs * xo.y + sn * xo.x);
  }
  if (tid == 0) { float2 z0 = src[0]; outp[1024] = make_float2(z0.x - z0.y, 0.0f); }
}

__global__ __launch_bounds__(256) void fk_dfft(const float2* __restrict__ specT,
                                               float2* __restrict__ sf) {
  const int b = blockIdx.y;
  const int f0 = blockIdx.x * 4;
  const int sub = threadIdx.x >> 6;
  const int i = threadIdx.x & 63;
  const int f = f0 + sub;
  const bool valid = (f < NF);
  __shared__ float2 A[4][128];
  __shared__ float2 Bf[4][128];
  if (valid) {
    const float2* col = specT + ((size_t)b * ND) * NF + f;
    A[sub][i]      = col[(size_t)i * NF];
    A[sub][i + 64] = col[(size_t)(i + 64) * NF];
  }
  __syncthreads();
  float2 (*src)[128] = A;
  float2 (*dst)[128] = Bf;
  for (int p = 1; p <= 64; p <<= 1) {
    if (valid) {
      int k = i & (p - 1);
      float2 u = src[sub][i];
      float2 v = src[sub][i + 64];
      float ang = -3.14159265358979323846f * ((float)k / (float)p);
      float sn, cs; __sincosf(ang, &sn, &cs);
      float2 vw = make_float2(v.x * cs - v.y * sn, v.x * sn + v.y * cs);
      int j = ((i - k) << 1) + k;
      dst[sub][j]     = make_float2(u.x + vw.x, u.y + vw.y);
      dst[sub][j + p] = make_float2(u.x - vw.x, u.y - vw.y);
    }
    __syncthreads();
    float2 (*t)[128] = src; src = dst; dst = t;
  }
  if (valid) {
    const float fwv = (f == 0 || f == NF - 1) ? 1.0f : 2.0f;
    double freqd = (double)f / 5.12e-5;
    float omega = (float)(freqd * 6.283185307179586);
    float woc = omega / 1540.0f;
    float woc2 = __fmul_rn(woc, woc);
    #pragma unroll
    for (int h = 0; h < 2; ++h) {
      int kd = i + h * 64;
      int kt = kd < 64 ? kd : kd - 128;
      float kxv = (float)(6.283185307179586 * ((double)kt / 0.0384));
      float kzsq = __fsub_rn(woc2, __fmul_rn(kxv, kxv));
      float m = (kzsq > 0.0f) ? fwv : 0.0f;
      float2 v = src[sub][kd];
      sf[((size_t)(b * ND + kd)) * NF + f] = make_float2(v.x * m, v.y * m);
    }
  }
}

__global__ __launch_bounds__(256, 3) void fk_band(const float2* __restrict__ sf,
                                                  unsigned int* __restrict__ bandh,
                                                  int flen_base, int fpad) {
  const int dblk = blockIdx.x;
  const int part = blockIdx.y;
  const int f0 = part * flen_base;
  const int flen = min(flen_base, NF - f0);
  const int tid = threadIdx.x;
  const int w = tid >> 6, l = tid & 63;
  const int d = dblk * 4 + w;
  extern __shared__ float lds[];
  float2* sfs = (float2*)lds;
  float4* kcs = (float4*)(lds + 64 * fpad);
  {
    const int row = tid >> 3;
    const int wr = row >> 3, br = row & 7;
    const int dr = dblk * 4 + wr;
    const float2* srcp = sf + ((size_t)(br * ND + dr)) * NF + f0;
    for (int ff = tid & 7; ff < fpad; ff += 8)
      sfs[row * fpad + ff] = (ff < flen) ? srcp[ff] : make_float2(0.f, 0.f);
  }
  for (int e = tid; e < 4 * fpad; e += 256) {
    const int wk = e / fpad, ff = e - wk * fpad;
    float kzv = 0.f;
    if (ff < flen) {
      int dk = dblk * 4 + wk;
      int kt = dk < 64 ? dk : dk - 128;
      float kxv = (float)(6.283185307179586 * ((double)kt / 0.0384));
      float kx2 = __fmul_rn(kxv, kxv);
      int f = f0 + ff;
      double freqd = (double)f / 5.12e-5;
      float omega = (float)(freqd * 6.283185307179586);
      float woc = omega / 1540.0f;
      float kzsq = __fsub_rn(__fmul_rn(woc, woc), kx2);
      kzv = (kzsq > 0.0f) ? sqrtf(kzsq) : 0.0f;
    }
    float sd, cd;
    __sincosf(kzv * 1.5e-4f, &sd, &cd);
    kcs[e] = make_float4(kzv, cd, sd, 0.f);
  }
  __syncthreads();
  const float y0 = (float)(1.0e-3 + (double)(4 * l) * 1.5e-4);
  float2 acc[8][4];
  #pragma unroll
  for (int b = 0; b < 8; ++b)
    #pragma unroll
    for (int i = 0; i < 4; ++i) acc[b][i] = make_float2(0.f, 0.f);
  const float4* kcw = kcs + w * fpad;
  const float2* rows = sfs + (w * 8) * fpad;
  #pragma unroll 2
  for (int ff = 0; ff < fpad; ++ff) {
    const float4 k4 = kcw[ff];
    float s0, c0;
    __sincosf(k4.x * y0, &s0, &c0);
    float2 ph[4];
    ph[0] = make_float2(c0, s0);
    #pragma unroll
    for (int i = 0; i < 3; ++i)
      ph[i + 1] = make_float2(ph[i].x * k4.y - ph[i].y * k4.z,
                              ph[i].x * k4.z + ph[i].y * k4.y);
    #pragma unroll
    for (int b = 0; b < 8; ++b) {
      float2 p = rows[b * fpad + ff];
      #pragma unroll
      for (int i = 0; i < 4; ++i) {
        acc[b][i].x = fmaf(p.x, ph[i].x, fmaf(-p.y, ph[i].y, acc[b][i].x));
        acc[b][i].y = fmaf(p.x, ph[i].y, fmaf( p.y, ph[i].x, acc[b][i].y));
      }
    }
  }
  unsigned int* outp = bandh + (size_t)part * (NB * ND * NYY);
  #pragma unroll
  for (int b = 0; b < 8; ++b) {
    uint4 pk;
    pk.x = bf16rne(acc[b][0].x) | (bf16rne(acc[b][0].y) << 16);
    pk.y = bf16rne(acc[b][1].x) | (bf16rne(acc[b][1].y) << 16);
    pk.z = bf16rne(acc[b][2].x) | (bf16rne(acc[b][2].y) << 16);
    pk.w = bf16rne(acc[b][3].x) | (bf16rne(acc[b][3].y) << 16);
    ((uint4*)(outp + ((size_t)(b * ND + d)) * NYY))[l] = pk;
  }
}

__global__ __launch_bounds__(256) void fk_sum(const unsigned int* __restrict__ bandh,
                                              float2* __restrict__ bandS, int nparts) {
  const int n = blockIdx.x * 256 + threadIdx.x;
  float sx = 0.f, sy = 0.f;
  for (int p = 0; p < nparts; ++p) {
    unsigned int u = bandh[(size_t)p * (NB * ND * NYY) + n];
    sx += __uint_as_float(u << 16);
    sy += __uint_as_float(u & 0xffff0000u);
  }
  bandS[n] = make_float2(sx, sy);
}

__global__ __launch_bounds__(256) void fk_img(const float2* __restrict__ bandS,
                                              const float2* __restrict__ rowstat,
                                              float* __restrict__ out, float inv_norm) {
  const int y0 = blockIdx.x * 2;
  const int b = blockIdx.y;
  const int tid = threadIdx.x;
  const int half = tid >> 7;
  const int t = tid & 127;
  __shared__ float2 A[2][256];
  __shared__ float2 Bb[2][256];
  __shared__ float2 spart[2];
  {
    float2 v = bandS[((size_t)(b * ND + t)) * NYY + (y0 + half)];
    A[half][t]       = (t < 64)  ? v : make_float2(0.f, 0.f);
    A[half][t + 128] = (t >= 64) ? v : make_float2(0.f, 0.f);
  }
  {
    float2 myrs = make_float2(0.f, 0.f);
    if (tid < 128) myrs = rowstat[b * ND + tid];
    float s = myrs.x, q = myrs.y;
    #pragma unroll
    for (int o = 32; o > 0; o >>= 1) { s += __shfl_down(s, o); q += __shfl_down(q, o); }
    if (tid < 128 && (tid & 63) == 0) spart[tid >> 6] = make_float2(s, q);
  }
  __syncthreads();
  const float nInv = 1.0f / 262144.0f;
  float ssum = spart[0].x + spart[1].x;
  float qsum = spart[0].y + spart[1].y;
  float mean = ssum * nInv;
  float var = qsum * nInv - mean * mean;
  float scl = 1.0f / sqrtf(var + 1.1920928955078125e-7f);
  float2 (*src)[256] = A;
  float2 (*dst)[256] = Bb;
  for (int p = 1; p <= 128; p <<= 1) {
    int i = t;
    int k = i & (p - 1);
    float2 u = src[half][i];
    float2 v = src[half][i + 128];
    float ang = 3.14159265358979323846f * ((float)k / (float)p);
    float sn, cs; __sincosf(ang, &sn, &cs);
    float2 vw = make_float2(v.x * cs - v.y * sn, v.x * sn + v.y * cs);
    int j = ((i - k) << 1) + k;
    dst[half][j]     = make_float2(u.x + vw.x, u.y + vw.y);
    dst[half][j + p] = make_float2(u.x - vw.x, u.y - vw.y);
    __syncthreads();
    float2 (*tt)[256] = src; src = dst; dst = tt;
  }
  float2 r0 = src[0][tid];
  float2 r1 = src[1][tid];
  out[((size_t)b * NYY + y0)     * NXX + tid] = sqrtf(r0.x * r0.x + r0.y * r0.y) * scl * inv_norm;
  out[((size_t)b * NYY + y0 + 1) * NXX + tid] = sqrtf(r1.x * r1.x + r1.y * r1.y) * scl * inv_norm;
}

extern "C" void kernel_launch(void* const* d_in, const int* in_sizes, int n_in,
                              void* d_out, int out_size, void* d_ws, size_t ws_size,
                              hipStream_t stream) {
  const float* sino = (const float*)d_in[0];
  float* out = (float*)d_out;
  char* ws = (char*)d_ws;

  unsigned*     bar     = (unsigned*)(ws + BAR_OFF);
  float2*       rowstat = (float2*)(ws + ROWSTAT_OFF);
  float2*       specT   = (float2*)(ws + SPECT_OFF);
  float2*       sf      = (float2*)(ws + SF_OFF);
  unsigned int* bandh   = (unsigned int*)(ws + BAND_OFF);

  double apod_sum = 0.0;
  for (int n = 0; n < ND; ++n) apod_sum += 0.5 - 0.5 * cos(6.283185307179586 * (double)n / 127.0);
  const float inv_norm = (float)(1.0 / (apod_sum * 2048.0));

  if (ws_size >= (size_t)NEED_MEGA) {
    float2* bandS = (float2*)(ws + BANDS_OFF);
    hipMemsetAsync(bar, 0, 64, stream);
    fk_mega<<<GRID_BLKS, 256, 0, stream>>>(sino, specT, rowstat, sf, bandh, bandS,
                                           out, bar, inv_norm);
  } else {
    // fallback: 5-kernel pipeline, FPART=8
    const int FP = 8;
    const int flen_base = (NF + FP - 1) / FP;          // 129
    const int fpad = (flen_base + 1) & ~1;             // 130
    const size_t band_lds = (size_t)fpad * 320;
    float2* bandS = (float2*)(ws + BAND_OFF + (size_t)FP * BANDH_PART_BYTES);
    fk_tfft<<<NB * ND, 256, 0, stream>>>(sino, specT, rowstat);
    fk_dfft<<<dim3((NF + 3) / 4, NB), 256, 0, stream>>>(specT, sf);
    fk_band<<<dim3(32, FP), 256, band_lds, stream>>>(sf, bandh, flen_base, fpad);
    fk_sum <<<NB * ND * NYY / 256, 256, 0, stream>>>(bandh, bandS, FP);
    fk_img <<<dim3(NYY / 2, NB), 256, 0, stream>>>(bandS, rowstat, out, inv_norm);
  }
}

// Round 16
// 76.647 us; speedup vs baseline: 5.0028x; 5.0028x over previous
//
#include <hip/hip_runtime.h>
#include <math.h>

#define NB 8
#define ND 128
#define NT 2048
#define NF 1025
#define NYY 256
#define NXX 256

#define SPEC_BYTES 8396800          /* 8*128*1025*8 */
#define BAND_PART_BYTES 2097152     /* 8*128*256*8 (fp32 bandS) */
#define BANDH_PART_BYTES 1048576    /* 8*128*256*4 (bf16x2 band part) */
#define ROWSTAT_OFF 0               /* 1024 float2 = 8KB */
#define SPECT_OFF  8192
#define SF_OFF     (SPECT_OFF + SPEC_BYTES)            /* 8,404,992 */
#define BAND_OFF   (SF_OFF + SPEC_BYTES)               /* 16,801,792 */

// ---------------- kernel 1: real 2048-pt rfft via 1024-pt complex FFT + untangle ----
// Also emits per-row raw (sum, sumsq) for the standardization scale (folded into fk_img).
__global__ __launch_bounds__(256) void fk_tfft(const float* __restrict__ sino,
                                               float2* __restrict__ specT,
                                               float2* __restrict__ rowstat) {
  const int row = blockIdx.x;      // b*ND + d
  const int d = row & (ND - 1);
  const int tid = threadIdx.x;
  __shared__ float2 bufA[1024];
  __shared__ float2 bufB[1024];
  __shared__ float2 wsum[4];
  const float ap = (float)(0.5 - 0.5 * cos(6.283185307179586 * (double)d / 127.0));
  const float2* in = (const float2*)(sino + (size_t)row * NT);   // z[n] = x[2n] + i x[2n+1]
  float s = 0.f, q = 0.f;
  for (int i = tid; i < 1024; i += 256) {
    float2 v = in[i];
    s += v.x + v.y;
    q += v.x * v.x + v.y * v.y;
    bufA[i] = make_float2(v.x * ap, v.y * ap);
  }
  #pragma unroll
  for (int o = 32; o > 0; o >>= 1) {
    s += __shfl_down(s, o);
    q += __shfl_down(q, o);
  }
  if ((tid & 63) == 0) wsum[tid >> 6] = make_float2(s, q);
  __syncthreads();
  if (tid == 0) {
    rowstat[row] = make_float2(wsum[0].x + wsum[1].x + wsum[2].x + wsum[3].x,
                               wsum[0].y + wsum[1].y + wsum[2].y + wsum[3].y);
  }
  float2* src = bufA;
  float2* dst = bufB;
  for (int p = 1; p <= 512; p <<= 1) {
    #pragma unroll
    for (int it = 0; it < 2; ++it) {
      int i = tid + it * 256;
      int k = i & (p - 1);
      float2 u = src[i];
      float2 v = src[i + 512];
      float ang = -3.14159265358979323846f * ((float)k / (float)p);
      float sn, cs; __sincosf(ang, &sn, &cs);
      float2 vw = make_float2(v.x * cs - v.y * sn, v.x * sn + v.y * cs);
      int j = ((i - k) << 1) + k;
      dst[j]     = make_float2(u.x + vw.x, u.y + vw.y);
      dst[j + p] = make_float2(u.x - vw.x, u.y - vw.y);
    }
    __syncthreads();
    float2* t = src; src = dst; dst = t;
  }
  // src = Z[0..1023]; untangle to rfft X[0..1024]
  float2* out = specT + (size_t)row * NF;
  for (int k = tid; k < 1024; k += 256) {
    float2 zk = src[k];
    float2 zc = src[(1024 - k) & 1023]; zc.y = -zc.y;          // conj
    float2 xe = make_float2(0.5f * (zk.x + zc.x), 0.5f * (zk.y + zc.y));
    float ax = zk.x - zc.x, ay = zk.y - zc.y;
    float2 xo = make_float2(0.5f * ay, -0.5f * ax);            // (Z - Zc)/(2i)
    float ang = -3.14159265358979323846f * ((float)k / 1024.0f);
    float sn, cs; __sincosf(ang, &sn, &cs);
    out[k] = make_float2(xe.x + cs * xo.x - sn * xo.y,
                         xe.y + cs * xo.y + sn * xo.x);
  }
  if (tid == 0) {
    float2 z0 = src[0];
    out[1024] = make_float2(z0.x - z0.y, 0.0f);
  }
}

// ---------------- kernel 2: detector FFT (128-pt) + prop_mask*fw ----------------
__global__ __launch_bounds__(256) void fk_dfft(const float2* __restrict__ specT,
                                               float2* __restrict__ sf) {
  const int b = blockIdx.y;
  const int f0 = blockIdx.x * 4;
  const int sub = threadIdx.x >> 6;   // 0..3 (which f)
  const int i = threadIdx.x & 63;     // butterfly index
  const int f = f0 + sub;
  const bool valid = (f < NF);
  __shared__ float2 A[4][128];
  __shared__ float2 Bf[4][128];
  if (valid) {
    const float2* col = specT + ((size_t)b * ND) * NF + f;
    A[sub][i]      = col[(size_t)i * NF];
    A[sub][i + 64] = col[(size_t)(i + 64) * NF];
  }
  __syncthreads();
  float2 (*src)[128] = A;
  float2 (*dst)[128] = Bf;
  for (int p = 1; p <= 64; p <<= 1) {
    if (valid) {
      int k = i & (p - 1);
      float2 u = src[sub][i];
      float2 v = src[sub][i + 64];
      float ang = -3.14159265358979323846f * ((float)k / (float)p);
      float sn, cs; __sincosf(ang, &sn, &cs);
      float2 vw = make_float2(v.x * cs - v.y * sn, v.x * sn + v.y * cs);
      int j = ((i - k) << 1) + k;
      dst[sub][j]     = make_float2(u.x + vw.x, u.y + vw.y);
      dst[sub][j + p] = make_float2(u.x - vw.x, u.y - vw.y);
    }
    __syncthreads();
    float2 (*t)[128] = src; src = dst; dst = t;
  }
  if (valid) {
    const float fwv = (f == 0 || f == NF - 1) ? 1.0f : 2.0f;
    double freqd = (double)f / 5.12e-5;
    float omega = (float)(freqd * 6.283185307179586);
    float woc = omega / 1540.0f;
    float woc2 = __fmul_rn(woc, woc);
    #pragma unroll
    for (int h = 0; h < 2; ++h) {
      int kd = i + h * 64;
      int kt = kd < 64 ? kd : kd - 128;
      float kxv = (float)(6.283185307179586 * ((double)kt / 0.0384));
      float kzsq = __fsub_rn(woc2, __fmul_rn(kxv, kxv));
      float m = (kzsq > 0.0f) ? fwv : 0.0f;
      float2 v = src[sub][kd];
      sf[((size_t)(b * ND + kd)) * NF + f] = make_float2(v.x * m, v.y * m);
    }
  }
}

__device__ __forceinline__ unsigned int bf16rne(float x) {
  unsigned int u = __float_as_uint(x);
  return (u + 0x7fffu + ((u >> 16) & 1u)) >> 16;
}

// ---------------- kernel 3: band_h[part][b][d][y] (bf16x2) = sum_f sf*exp(i*kz*y) ----
// Wave w owns d = dblk*4+w; thread owns 4 consecutive y. Staging precomputes
// {kz, cos(kz*dy), sin(kz*dy)} so the inner loop has ONE sincos + 3 cmuls.
__global__ __launch_bounds__(256, 3) void fk_band(const float2* __restrict__ sf,
                                                  unsigned int* __restrict__ bandh,
                                                  int flen_base, int fpad) {
  const int dblk = blockIdx.x;   // 0..31
  const int part = blockIdx.y;   // 0..FPART-1
  const int f0 = part * flen_base;
  const int flen = min(flen_base, NF - f0);
  const int tid = threadIdx.x;
  const int w = tid >> 6, l = tid & 63;
  const int d = dblk * 4 + w;

  extern __shared__ float lds[];
  float2* sfs = (float2*)lds;                  // [32 rows][fpad]  row = w*8+b
  float4* kcs = (float4*)(lds + 64 * fpad);    // [4][fpad] {kz, cd, sd, -}

  // stage sf rows (8-thread runs per row)
  {
    const int row = tid >> 3;            // 0..31
    const int wr = row >> 3, br = row & 7;
    const int dr = dblk * 4 + wr;
    const float2* srcp = sf + ((size_t)(br * ND + dr)) * NF + f0;
    for (int ff = tid & 7; ff < fpad; ff += 8)
      sfs[row * fpad + ff] = (ff < flen) ? srcp[ff] : make_float2(0.f, 0.f);
  }
  // stage kz + uniform delta-phase per wave-d
  for (int e = tid; e < 4 * fpad; e += 256) {
    const int wk = e / fpad, ff = e - wk * fpad;
    float kzv = 0.f;
    if (ff < flen) {
      int dk = dblk * 4 + wk;
      int kt = dk < 64 ? dk : dk - 128;
      float kxv = (float)(6.283185307179586 * ((double)kt / 0.0384));
      float kx2 = __fmul_rn(kxv, kxv);
      int f = f0 + ff;
      double freqd = (double)f / 5.12e-5;
      float omega = (float)(freqd * 6.283185307179586);
      float woc = omega / 1540.0f;
      float kzsq = __fsub_rn(__fmul_rn(woc, woc), kx2);
      kzv = (kzsq > 0.0f) ? sqrtf(kzsq) : 0.0f;
    }
    float sd, cd;
    __sincosf(kzv * 1.5e-4f, &sd, &cd);
    kcs[e] = make_float4(kzv, cd, sd, 0.f);
  }
  __syncthreads();

  const float y0 = (float)(1.0e-3 + (double)(4 * l) * 1.5e-4);

  float2 acc[8][4];
  #pragma unroll
  for (int b = 0; b < 8; ++b)
    #pragma unroll
    for (int i = 0; i < 4; ++i) acc[b][i] = make_float2(0.f, 0.f);

  const float4* kcw = kcs + w * fpad;
  const float2* rows = sfs + (w * 8) * fpad;

  #pragma unroll 2
  for (int ff = 0; ff < fpad; ++ff) {
    const float4 k4 = kcw[ff];                     // uniform b128 broadcast
    float s0, c0;
    __sincosf(k4.x * y0, &s0, &c0);
    float2 ph[4];
    ph[0] = make_float2(c0, s0);
    #pragma unroll
    for (int i = 0; i < 3; ++i)
      ph[i + 1] = make_float2(ph[i].x * k4.y - ph[i].y * k4.z,
                              ph[i].x * k4.z + ph[i].y * k4.y);
    #pragma unroll
    for (int b = 0; b < 8; ++b) {
      float2 p = rows[b * fpad + ff];              // uniform broadcast b64
      #pragma unroll
      for (int i = 0; i < 4; ++i) {
        acc[b][i].x = fmaf(p.x, ph[i].x, fmaf(-p.y, ph[i].y, acc[b][i].x));
        acc[b][i].y = fmaf(p.x, ph[i].y, fmaf( p.y, ph[i].x, acc[b][i].y));
      }
    }
  }

  unsigned int* outp = bandh + (size_t)part * (NB * ND * NYY);
  #pragma unroll
  for (int b = 0; b < 8; ++b) {
    uint4 pk;
    pk.x = bf16rne(acc[b][0].x) | (bf16rne(acc[b][0].y) << 16);
    pk.y = bf16rne(acc[b][1].x) | (bf16rne(acc[b][1].y) << 16);
    pk.z = bf16rne(acc[b][2].x) | (bf16rne(acc[b][2].y) << 16);
    pk.w = bf16rne(acc[b][3].x) | (bf16rne(acc[b][3].y) << 16);
    ((uint4*)(outp + ((size_t)(b * ND + d)) * NYY))[l] = pk;   // 16B/lane coalesced
  }
}

// ---------------- kernel 4: bandS[b][d][y] (fp32) = sum_part band_h ----------------
__global__ __launch_bounds__(256) void fk_sum(const unsigned int* __restrict__ bandh,
                                              float2* __restrict__ bandS, int nparts) {
  const int n = blockIdx.x * 256 + threadIdx.x;   // [b][d][y], coalesced both sides
  float sx = 0.f, sy = 0.f;
  for (int p = 0; p < nparts; ++p) {
    unsigned int u = bandh[(size_t)p * (NB * ND * NYY) + n];
    sx += __uint_as_float(u << 16);
    sy += __uint_as_float(u & 0xffff0000u);
  }
  bandS[n] = make_float2(sx, sy);
}

// ---------------- kernel 5: lateral 256-pt inverse FFT + magnitude + scale ----------
// Two y-rows per block: all 256 threads active in every butterfly stage.
__global__ __launch_bounds__(256) void fk_img(const float2* __restrict__ bandS,
                                              const float2* __restrict__ rowstat,
                                              float* __restrict__ out, float inv_norm) {
  const int y0 = blockIdx.x * 2;
  const int b = blockIdx.y;
  const int tid = threadIdx.x;
  const int half = tid >> 7;       // which y-row
  const int t = tid & 127;
  __shared__ float2 A[2][256];
  __shared__ float2 Bb[2][256];
  __shared__ float2 spart[2];
  {
    // S[md]=band[d], md = d<64 ? d : d+128; zeros elsewhere
    float2 v = bandS[((size_t)(b * ND + t)) * NYY + (y0 + half)];
    A[half][t]       = (t < 64)  ? v : make_float2(0.f, 0.f);
    A[half][t + 128] = (t >= 64) ? v : make_float2(0.f, 0.f);
  }
  {
    float2 myrs = make_float2(0.f, 0.f);
    if (tid < 128) myrs = rowstat[b * ND + tid];
    float s = myrs.x, q = myrs.y;
    #pragma unroll
    for (int o = 32; o > 0; o >>= 1) {
      s += __shfl_down(s, o);
      q += __shfl_down(q, o);
    }
    if (tid < 128 && (tid & 63) == 0) spart[tid >> 6] = make_float2(s, q);
  }
  __syncthreads();
  const float nInv = 1.0f / 262144.0f;
  float ssum = spart[0].x + spart[1].x;
  float qsum = spart[0].y + spart[1].y;
  float mean = ssum * nInv;
  float var = qsum * nInv - mean * mean;
  float scl = 1.0f / sqrtf(var + 1.1920928955078125e-7f);

  float2 (*src)[256] = A;
  float2 (*dst)[256] = Bb;
  for (int p = 1; p <= 128; p <<= 1) {
    int i = t;
    int k = i & (p - 1);
    float2 u = src[half][i];
    float2 v = src[half][i + 128];
    float ang = 3.14159265358979323846f * ((float)k / (float)p);   // +: inverse
    float sn, cs; __sincosf(ang, &sn, &cs);
    float2 vw = make_float2(v.x * cs - v.y * sn, v.x * sn + v.y * cs);
    int j = ((i - k) << 1) + k;
    dst[half][j]     = make_float2(u.x + vw.x, u.y + vw.y);
    dst[half][j + p] = make_float2(u.x - vw.x, u.y - vw.y);
    __syncthreads();
    float2 (*tt)[256] = src; src = dst; dst = tt;
  }
  float2 r0 = src[0][tid];
  float2 r1 = src[1][tid];
  out[((size_t)b * NYY + y0)     * NXX + tid] = sqrtf(r0.x * r0.x + r0.y * r0.y) * scl * inv_norm;
  out[((size_t)b * NYY + y0 + 1) * NXX + tid] = sqrtf(r1.x * r1.x + r1.y * r1.y) * scl * inv_norm;
}

extern "C" void kernel_launch(void* const* d_in, const int* in_sizes, int n_in,
                              void* d_out, int out_size, void* d_ws, size_t ws_size,
                              hipStream_t stream) {
  const float* sino = (const float*)d_in[0];
  float* out = (float*)d_out;
  char* ws = (char*)d_ws;

  float2*       rowstat = (float2*)(ws + ROWSTAT_OFF);
  float2*       specT   = (float2*)(ws + SPECT_OFF);
  float2*       sf      = (float2*)(ws + SF_OFF);
  unsigned int* bandh   = (unsigned int*)(ws + BAND_OFF);

  // f-partition tier from ws_size (deterministic)
  int FPART = 8;
  if (ws_size >= (size_t)BAND_OFF + 24u * BANDH_PART_BYTES + BAND_PART_BYTES) FPART = 24;
  const int flen_base = (NF + FPART - 1) / FPART;     // 43 / 129
  const int fpad = (flen_base + 1) & ~1;              // 44 / 130
  const size_t band_lds = (size_t)fpad * 320;         // 32*8B + 16B per ff
  float2* bandS = (float2*)(ws + BAND_OFF + (size_t)FPART * BANDH_PART_BYTES);

  double apod_sum = 0.0;
  for (int n = 0; n < ND; ++n) apod_sum += 0.5 - 0.5 * cos(6.283185307179586 * (double)n / 127.0);
  const float inv_norm = (float)(1.0 / (apod_sum * 2048.0));

  fk_tfft<<<NB * ND, 256, 0, stream>>>(sino, specT, rowstat);
  fk_dfft<<<dim3((NF + 3) / 4, NB), 256, 0, stream>>>(specT, sf);
  fk_band<<<dim3(32, FPART), 256, band_lds, stream>>>(sf, bandh, flen_base, fpad);
  fk_sum <<<NB * ND * NYY / 256, 256, 0, stream>>>(bandh, bandS, FPART);
  fk_img <<<dim3(NYY / 2, NB), 256, 0, stream>>>(bandS, rowstat, out, inv_norm);
}

// Round 17
// 63.236 us; speedup vs baseline: 6.0637x; 1.2121x over previous
//
#include <hip/hip_runtime.h>
#include <hip/hip_bf16.h>
#include <math.h>

#define NB 8
#define ND 128
#define NT 2048
#define NF 1025
#define NYY 256
#define NXX 256

#define SPEC_BYTES 8396800          /* 8*128*1025*8 */
#define BAND_PART_BYTES 2097152     /* 8*128*256*8 (fp32 bandS) */
#define BANDH_PART_BYTES 1048576    /* 8*128*256*4 (bf16x2 band part) */
#define ROWSTAT_OFF 0               /* 1024 float2 = 8KB */
#define SPECT_OFF  8192
#define SF_OFF     (SPECT_OFF + SPEC_BYTES)            /* 8,404,992 */
#define BAND_OFF   (SF_OFF + SPEC_BYTES)               /* 16,801,792 */

typedef short bf16x8 __attribute__((ext_vector_type(8)));
typedef float f32x4 __attribute__((ext_vector_type(4)));

__device__ __forceinline__ unsigned pk2bf(float lo, float hi) {
  __hip_bfloat162 h = __float22bfloat162_rn(make_float2(lo, hi));
  unsigned u;
  __builtin_memcpy(&u, &h, 4);
  return u;
}

// ---------------- kernel 1: real 2048-pt rfft via 1024-pt complex FFT + untangle ----
__global__ __launch_bounds__(256) void fk_tfft(const float* __restrict__ sino,
                                               float2* __restrict__ specT,
                                               float2* __restrict__ rowstat) {
  const int row = blockIdx.x;      // b*ND + d
  const int d = row & (ND - 1);
  const int tid = threadIdx.x;
  __shared__ float2 bufA[1024];
  __shared__ float2 bufB[1024];
  __shared__ float2 wsum[4];
  const float ap = (float)(0.5 - 0.5 * cos(6.283185307179586 * (double)d / 127.0));
  const float2* in = (const float2*)(sino + (size_t)row * NT);   // z[n] = x[2n] + i x[2n+1]
  float s = 0.f, q = 0.f;
  for (int i = tid; i < 1024; i += 256) {
    float2 v = in[i];
    s += v.x + v.y;
    q += v.x * v.x + v.y * v.y;
    bufA[i] = make_float2(v.x * ap, v.y * ap);
  }
  #pragma unroll
  for (int o = 32; o > 0; o >>= 1) {
    s += __shfl_down(s, o);
    q += __shfl_down(q, o);
  }
  if ((tid & 63) == 0) wsum[tid >> 6] = make_float2(s, q);
  __syncthreads();
  if (tid == 0) {
    rowstat[row] = make_float2(wsum[0].x + wsum[1].x + wsum[2].x + wsum[3].x,
                               wsum[0].y + wsum[1].y + wsum[2].y + wsum[3].y);
  }
  float2* src = bufA;
  float2* dst = bufB;
  for (int p = 1; p <= 512; p <<= 1) {
    #pragma unroll
    for (int it = 0; it < 2; ++it) {
      int i = tid + it * 256;
      int k = i & (p - 1);
      float2 u = src[i];
      float2 v = src[i + 512];
      float ang = -3.14159265358979323846f * ((float)k / (float)p);
      float sn, cs; __sincosf(ang, &sn, &cs);
      float2 vw = make_float2(v.x * cs - v.y * sn, v.x * sn + v.y * cs);
      int j = ((i - k) << 1) + k;
      dst[j]     = make_float2(u.x + vw.x, u.y + vw.y);
      dst[j + p] = make_float2(u.x - vw.x, u.y - vw.y);
    }
    __syncthreads();
    float2* t = src; src = dst; dst = t;
  }
  float2* out = specT + (size_t)row * NF;
  for (int k = tid; k < 1024; k += 256) {
    float2 zk = src[k];
    float2 zc = src[(1024 - k) & 1023]; zc.y = -zc.y;          // conj
    float2 xe = make_float2(0.5f * (zk.x + zc.x), 0.5f * (zk.y + zc.y));
    float ax = zk.x - zc.x, ay = zk.y - zc.y;
    float2 xo = make_float2(0.5f * ay, -0.5f * ax);            // (Z - Zc)/(2i)
    float ang = -3.14159265358979323846f * ((float)k / 1024.0f);
    float sn, cs; __sincosf(ang, &sn, &cs);
    out[k] = make_float2(xe.x + cs * xo.x - sn * xo.y,
                         xe.y + cs * xo.y + sn * xo.x);
  }
  if (tid == 0) {
    float2 z0 = src[0];
    out[1024] = make_float2(z0.x - z0.y, 0.0f);
  }
}

// ---------------- kernel 2: detector FFT (128-pt) + prop_mask*fw ----------------
__global__ __launch_bounds__(256) void fk_dfft(const float2* __restrict__ specT,
                                               float2* __restrict__ sf) {
  const int b = blockIdx.y;
  const int f0 = blockIdx.x * 4;
  const int sub = threadIdx.x >> 6;   // 0..3 (which f)
  const int i = threadIdx.x & 63;     // butterfly index
  const int f = f0 + sub;
  const bool valid = (f < NF);
  __shared__ float2 A[4][128];
  __shared__ float2 Bf[4][128];
  if (valid) {
    const float2* col = specT + ((size_t)b * ND) * NF + f;
    A[sub][i]      = col[(size_t)i * NF];
    A[sub][i + 64] = col[(size_t)(i + 64) * NF];
  }
  __syncthreads();
  float2 (*src)[128] = A;
  float2 (*dst)[128] = Bf;
  for (int p = 1; p <= 64; p <<= 1) {
    if (valid) {
      int k = i & (p - 1);
      float2 u = src[sub][i];
      float2 v = src[sub][i + 64];
      float ang = -3.14159265358979323846f * ((float)k / (float)p);
      float sn, cs; __sincosf(ang, &sn, &cs);
      float2 vw = make_float2(v.x * cs - v.y * sn, v.x * sn + v.y * cs);
      int j = ((i - k) << 1) + k;
      dst[sub][j]     = make_float2(u.x + vw.x, u.y + vw.y);
      dst[sub][j + p] = make_float2(u.x - vw.x, u.y - vw.y);
    }
    __syncthreads();
    float2 (*t)[128] = src; src = dst; dst = t;
  }
  if (valid) {
    const float fwv = (f == 0 || f == NF - 1) ? 1.0f : 2.0f;
    double freqd = (double)f / 5.12e-5;
    float omega = (float)(freqd * 6.283185307179586);
    float woc = omega / 1540.0f;
    float woc2 = __fmul_rn(woc, woc);
    #pragma unroll
    for (int h = 0; h < 2; ++h) {
      int kd = i + h * 64;
      int kt = kd < 64 ? kd : kd - 128;
      float kxv = (float)(6.283185307179586 * ((double)kt / 0.0384));
      float kzsq = __fsub_rn(woc2, __fmul_rn(kxv, kxv));
      float m = (kzsq > 0.0f) ? fwv : 0.0f;
      float2 v = src[sub][kd];
      sf[((size_t)(b * ND + kd)) * NF + f] = make_float2(v.x * m, v.y * m);
    }
  }
}

__device__ __forceinline__ unsigned int bf16rne(float x) {
  unsigned int u = __float_as_uint(x);
  return (u + 0x7fffu + ((u >> 16) & 1u)) >> 16;
}

// ---------------- kernel 3 (MFMA): band_h[part][b][d][y] = sum_f sf*exp(i*kz*y) ----
// Per wave: one d; two real GEMMs (re/im) of A[256 y x 96 k] * B[96 k x 16].
// A = E_re/E_im interleaved in K, built via y-recurrence (E[y+16] = E[y]*step16).
// B cols 0..7 = batches (re-out or im-out combos), cols 8..15 = 0.
// C layout (m89-verified): col = lane&15, row = (lane>>4)*4 + reg.
__global__ __launch_bounds__(256, 3) void fk_band_mfma(const float2* __restrict__ sf,
                                                       unsigned int* __restrict__ bandh,
                                                       int flen_base) {
  const int dblk = blockIdx.x;   // 0..31
  const int part = blockIdx.y;   // 0..23
  const int f0 = part * flen_base;
  const int flen = min(flen_base, NF - f0);
  const int tid = threadIdx.x;
  const int lane = tid & 63;
  const int d = dblk * 4 + (tid >> 6);
  const int col = lane & 15;     // B col: batch (0..7 active)
  const int grp = lane >> 4;     // k-quarter

  // Build per-lane kz table and B-fragments. k = grp*8 + j, f_local = k>>1.
  float kzv[3][4];
  bf16x8 bfr[3], bfi[3];
  #pragma unroll
  for (int kt = 0; kt < 3; ++kt) {
    union { unsigned u[4]; bf16x8 v; } ur, ui;
    #pragma unroll
    for (int c = 0; c < 4; ++c) {
      const int fl = kt * 16 + grp * 4 + c;
      float kv = 0.f;
      float2 s = make_float2(0.f, 0.f);
      if (fl < flen) {
        const int fg = f0 + fl;
        int ktd = d < 64 ? d : d - 128;
        float kxv = (float)(6.283185307179586 * ((double)ktd / 0.0384));
        float kx2 = __fmul_rn(kxv, kxv);
        double freqd = (double)fg / 5.12e-5;
        float omega = (float)(freqd * 6.283185307179586);
        float woc = omega / 1540.0f;
        float kzsq = __fsub_rn(__fmul_rn(woc, woc), kx2);
        kv = (kzsq > 0.0f) ? sqrtf(kzsq) : 0.0f;
        if (col < 8) s = sf[((size_t)(col * ND + d)) * NF + fg];
      }
      kzv[kt][c] = kv;
      ur.u[c] = pk2bf(s.x, -s.y);   // re-out: E_re*sf_re - E_im*sf_im
      ui.u[c] = pk2bf(s.y,  s.x);   // im-out: E_re*sf_im + E_im*sf_re
    }
    bfr[kt] = ur.v;
    bfi[kt] = ui.v;
  }

  const float stepf = 2.4e-3f;     // 16 * dy
  const int arow = lane & 15;      // A row within 16-row M tile
  const f32x4 zz = {0.f, 0.f, 0.f, 0.f};

  #pragma unroll
  for (int h = 0; h < 2; ++h) {
    f32x4 accre[8], accim[8];
    #pragma unroll
    for (int m = 0; m < 8; ++m) { accre[m] = zz; accim[m] = zz; }
    const float yv0 = (float)(1.0e-3 + (double)(h * 128 + arow) * 1.5e-4);
    #pragma unroll
    for (int kt = 0; kt < 3; ++kt) {
      float2 cur[4], stp[4];
      #pragma unroll
      for (int c = 0; c < 4; ++c) {
        float sn, cs;
        __sincosf(kzv[kt][c] * yv0, &sn, &cs);
        cur[c] = make_float2(cs, sn);
        __sincosf(kzv[kt][c] * stepf, &sn, &cs);
        stp[c] = make_float2(cs, sn);
      }
      #pragma unroll
      for (int m = 0; m < 8; ++m) {
        union { unsigned u[4]; bf16x8 v; } ua;
        #pragma unroll
        for (int c = 0; c < 4; ++c) ua.u[c] = pk2bf(cur[c].x, cur[c].y);
        accre[m] = __builtin_amdgcn_mfma_f32_16x16x32_bf16(ua.v, bfr[kt], accre[m], 0, 0, 0);
        accim[m] = __builtin_amdgcn_mfma_f32_16x16x32_bf16(ua.v, bfi[kt], accim[m], 0, 0, 0);
        #pragma unroll
        for (int c = 0; c < 4; ++c) {
          float2 nc;
          nc.x = cur[c].x * stp[c].x - cur[c].y * stp[c].y;
          nc.y = cur[c].x * stp[c].y + cur[c].y * stp[c].x;
          cur[c] = nc;
        }
      }
    }
    if (col < 8) {
      unsigned int* outp = bandh + (size_t)part * (NB * ND * NYY)
                         + ((size_t)(col * ND + d)) * NYY;
      #pragma unroll
      for (int m = 0; m < 8; ++m) {
        const int y0 = h * 128 + m * 16 + grp * 4;   // C row = grp*4 + reg
        uint4 pk;
        pk.x = pk2bf(accre[m][0], accim[m][0]);
        pk.y = pk2bf(accre[m][1], accim[m][1]);
        pk.z = pk2bf(accre[m][2], accim[m][2]);
        pk.w = pk2bf(accre[m][3], accim[m][3]);
        *(uint4*)(outp + y0) = pk;
      }
    }
  }
}

// ---------------- kernel 3-fallback (VALU band, small-ws path) ----------------
__global__ __launch_bounds__(256, 3) void fk_band(const float2* __restrict__ sf,
                                                  unsigned int* __restrict__ bandh,
                                                  int flen_base, int fpad) {
  const int dblk = blockIdx.x;
  const int part = blockIdx.y;
  const int f0 = part * flen_base;
  const int flen = min(flen_base, NF - f0);
  const int tid = threadIdx.x;
  const int w = tid >> 6, l = tid & 63;
  const int d = dblk * 4 + w;
  extern __shared__ float lds[];
  float2* sfs = (float2*)lds;
  float4* kcs = (float4*)(lds + 64 * fpad);
  {
    const int row = tid >> 3;
    const int wr = row >> 3, br = row & 7;
    const int dr = dblk * 4 + wr;
    const float2* srcp = sf + ((size_t)(br * ND + dr)) * NF + f0;
    for (int ff = tid & 7; ff < fpad; ff += 8)
      sfs[row * fpad + ff] = (ff < flen) ? srcp[ff] : make_float2(0.f, 0.f);
  }
  for (int e = tid; e < 4 * fpad; e += 256) {
    const int wk = e / fpad, ff = e - wk * fpad;
    float kzv = 0.f;
    if (ff < flen) {
      int dk = dblk * 4 + wk;
      int kt = dk < 64 ? dk : dk - 128;
      float kxv = (float)(6.283185307179586 * ((double)kt / 0.0384));
      float kx2 = __fmul_rn(kxv, kxv);
      int f = f0 + ff;
      double freqd = (double)f / 5.12e-5;
      float omega = (float)(freqd * 6.283185307179586);
      float woc = omega / 1540.0f;
      float kzsq = __fsub_rn(__fmul_rn(woc, woc), kx2);
      kzv = (kzsq > 0.0f) ? sqrtf(kzsq) : 0.0f;
    }
    float sd, cd;
    __sincosf(kzv * 1.5e-4f, &sd, &cd);
    kcs[e] = make_float4(kzv, cd, sd, 0.f);
  }
  __syncthreads();
  const float y0 = (float)(1.0e-3 + (double)(4 * l) * 1.5e-4);
  float2 acc[8][4];
  #pragma unroll
  for (int b = 0; b < 8; ++b)
    #pragma unroll
    for (int i = 0; i < 4; ++i) acc[b][i] = make_float2(0.f, 0.f);
  const float4* kcw = kcs + w * fpad;
  const float2* rows = sfs + (w * 8) * fpad;
  #pragma unroll 2
  for (int ff = 0; ff < fpad; ++ff) {
    const float4 k4 = kcw[ff];
    float s0, c0;
    __sincosf(k4.x * y0, &s0, &c0);
    float2 ph[4];
    ph[0] = make_float2(c0, s0);
    #pragma unroll
    for (int i = 0; i < 3; ++i)
      ph[i + 1] = make_float2(ph[i].x * k4.y - ph[i].y * k4.z,
                              ph[i].x * k4.z + ph[i].y * k4.y);
    #pragma unroll
    for (int b = 0; b < 8; ++b) {
      float2 p = rows[b * fpad + ff];
      #pragma unroll
      for (int i = 0; i < 4; ++i) {
        acc[b][i].x = fmaf(p.x, ph[i].x, fmaf(-p.y, ph[i].y, acc[b][i].x));
        acc[b][i].y = fmaf(p.x, ph[i].y, fmaf( p.y, ph[i].x, acc[b][i].y));
      }
    }
  }
  unsigned int* outp = bandh + (size_t)part * (NB * ND * NYY);
  #pragma unroll
  for (int b = 0; b < 8; ++b) {
    uint4 pk;
    pk.x = bf16rne(acc[b][0].x) | (bf16rne(acc[b][0].y) << 16);
    pk.y = bf16rne(acc[b][1].x) | (bf16rne(acc[b][1].y) << 16);
    pk.z = bf16rne(acc[b][2].x) | (bf16rne(acc[b][2].y) << 16);
    pk.w = bf16rne(acc[b][3].x) | (bf16rne(acc[b][3].y) << 16);
    ((uint4*)(outp + ((size_t)(b * ND + d)) * NYY))[l] = pk;
  }
}

// ---------------- kernel 4: bandS[b][d][y] (fp32) = sum_part band_h ----------------
__global__ __launch_bounds__(256) void fk_sum(const unsigned int* __restrict__ bandh,
                                              float2* __restrict__ bandS, int nparts) {
  const int n = blockIdx.x * 256 + threadIdx.x;   // [b][d][y], coalesced both sides
  float sx = 0.f, sy = 0.f;
  for (int p = 0; p < nparts; ++p) {
    unsigned int u = bandh[(size_t)p * (NB * ND * NYY) + n];
    sx += __uint_as_float(u << 16);
    sy += __uint_as_float(u & 0xffff0000u);
  }
  bandS[n] = make_float2(sx, sy);
}

// ---------------- kernel 5: lateral 256-pt inverse FFT + magnitude + scale ----------
__global__ __launch_bounds__(256) void fk_img(const float2* __restrict__ bandS,
                                              const float2* __restrict__ rowstat,
                                              float* __restrict__ out, float inv_norm) {
  const int y0 = blockIdx.x * 2;
  const int b = blockIdx.y;
  const int tid = threadIdx.x;
  const int half = tid >> 7;       // which y-row
  const int t = tid & 127;
  __shared__ float2 A[2][256];
  __shared__ float2 Bb[2][256];
  __shared__ float2 spart[2];
  {
    float2 v = bandS[((size_t)(b * ND + t)) * NYY + (y0 + half)];
    A[half][t]       = (t < 64)  ? v : make_float2(0.f, 0.f);
    A[half][t + 128] = (t >= 64) ? v : make_float2(0.f, 0.f);
  }
  {
    float2 myrs = make_float2(0.f, 0.f);
    if (tid < 128) myrs = rowstat[b * ND + tid];
    float s = myrs.x, q = myrs.y;
    #pragma unroll
    for (int o = 32; o > 0; o >>= 1) {
      s += __shfl_down(s, o);
      q += __shfl_down(q, o);
    }
    if (tid < 128 && (tid & 63) == 0) spart[tid >> 6] = make_float2(s, q);
  }
  __syncthreads();
  const float nInv = 1.0f / 262144.0f;
  float ssum = spart[0].x + spart[1].x;
  float qsum = spart[0].y + spart[1].y;
  float mean = ssum * nInv;
  float var = qsum * nInv - mean * mean;
  float scl = 1.0f / sqrtf(var + 1.1920928955078125e-7f);

  float2 (*src)[256] = A;
  float2 (*dst)[256] = Bb;
  for (int p = 1; p <= 128; p <<= 1) {
    int i = t;
    int k = i & (p - 1);
    float2 u = src[half][i];
    float2 v = src[half][i + 128];
    float ang = 3.14159265358979323846f * ((float)k / (float)p);   // +: inverse
    float sn, cs; __sincosf(ang, &sn, &cs);
    float2 vw = make_float2(v.x * cs - v.y * sn, v.x * sn + v.y * cs);
    int j = ((i - k) << 1) + k;
    dst[half][j]     = make_float2(u.x + vw.x, u.y + vw.y);
    dst[half][j + p] = make_float2(u.x - vw.x, u.y - vw.y);
    __syncthreads();
    float2 (*tt)[256] = src; src = dst; dst = tt;
  }
  float2 r0 = src[0][tid];
  float2 r1 = src[1][tid];
  out[((size_t)b * NYY + y0)     * NXX + tid] = sqrtf(r0.x * r0.x + r0.y * r0.y) * scl * inv_norm;
  out[((size_t)b * NYY + y0 + 1) * NXX + tid] = sqrtf(r1.x * r1.x + r1.y * r1.y) * scl * inv_norm;
}

extern "C" void kernel_launch(void* const* d_in, const int* in_sizes, int n_in,
                              void* d_out, int out_size, void* d_ws, size_t ws_size,
                              hipStream_t stream) {
  const float* sino = (const float*)d_in[0];
  float* out = (float*)d_out;
  char* ws = (char*)d_ws;

  float2*       rowstat = (float2*)(ws + ROWSTAT_OFF);
  float2*       specT   = (float2*)(ws + SPECT_OFF);
  float2*       sf      = (float2*)(ws + SF_OFF);
  unsigned int* bandh   = (unsigned int*)(ws + BAND_OFF);

  double apod_sum = 0.0;
  for (int n = 0; n < ND; ++n) apod_sum += 0.5 - 0.5 * cos(6.283185307179586 * (double)n / 127.0);
  const float inv_norm = (float)(1.0 / (apod_sum * 2048.0));

  fk_tfft<<<NB * ND, 256, 0, stream>>>(sino, specT, rowstat);
  fk_dfft<<<dim3((NF + 3) / 4, NB), 256, 0, stream>>>(specT, sf);

  if (ws_size >= (size_t)BAND_OFF + 24u * BANDH_PART_BYTES + BAND_PART_BYTES) {
    const int FPART = 24;
    const int flen_base = (NF + FPART - 1) / FPART;   // 43 -> K=86, 3 K-tiles of 32
    float2* bandS = (float2*)(ws + BAND_OFF + (size_t)FPART * BANDH_PART_BYTES);
    fk_band_mfma<<<dim3(32, FPART), 256, 0, stream>>>(sf, bandh, flen_base);
    fk_sum<<<NB * ND * NYY / 256, 256, 0, stream>>>(bandh, bandS, FPART);
    fk_img<<<dim3(NYY / 2, NB), 256, 0, stream>>>(bandS, rowstat, out, inv_norm);
  } else {
    const int FPART = 8;
    const int flen_base = (NF + FPART - 1) / FPART;   // 129
    const int fpad = (flen_base + 1) & ~1;            // 130
    const size_t band_lds = (size_t)fpad * 320;
    float2* bandS = (float2*)(ws + BAND_OFF + (size_t)FPART * BANDH_PART_BYTES);
    fk_band<<<dim3(32, FPART), 256, band_lds, stream>>>(sf, bandh, flen_base, fpad);
    fk_sum<<<NB * ND * NYY / 256, 256, 0, stream>>>(bandh, bandS, FPART);
    fk_img<<<dim3(NYY / 2, NB), 256, 0, stream>>>(bandS, rowstat, out, inv_norm);
  }
}